// Round 1
// baseline (475.472 us; speedup 1.0000x reference)
//
#include <hip/hip_runtime.h>
#include <cfloat>
#include <cmath>

// Problem constants
#define H  1024
#define V  50257
#define L  128
#define NB4 ((V + 3) / 4)          // 12565 blocks for logits GEMV (4 rows/block)

// ws layout (float offsets). Total ~79.6K floats (~318 KB).
#define WS_COMB_IN 0                       // embedded[1024] ++ attn_applied[1024]
#define WS_X       2048                    // relu(comb) [1024]
#define WS_H       3072                    // h_new [1024]
#define WS_ATTN    4096                    // attn weights [128]
#define WS_LOGITS  4224                    // logits [V], padded to 50260
#define WS_PM      (WS_LOGITS + 50260)     // per-block max [NB4], padded 12568
#define WS_PS      (WS_PM + 12568)         // per-block sumexp [NB4], padded 12568
#define WS_LS      (WS_PS + 12568)         // scalar logsumexp

__device__ __forceinline__ float dot4(float4 a, float4 b) {
    return a.x * b.x + a.y * b.y + a.z * b.z + a.w * b.w;
}

__device__ __forceinline__ float wave_sum(float acc) {
    #pragma unroll
    for (int off = 32; off > 0; off >>= 1) acc += __shfl_down(acc, off);
    return acc;
}

__device__ __forceinline__ float sigmoidf(float x) {
    return 1.f / (1.f + expf(-x));
}

// K1: attention scores + softmax. 1 block x 1024 threads (16 waves).
__global__ __launch_bounds__(1024) void k_attn(const int* __restrict__ tokens,
                                               const float* __restrict__ h0,
                                               const float* __restrict__ emb,
                                               const float* __restrict__ attn_W,
                                               const float* __restrict__ attn_b,
                                               float* __restrict__ ws,
                                               float* __restrict__ dout) {
    __shared__ float4 sin4[512];           // attn_in = [embedded, h], 2048 floats
    __shared__ float  sc[L];
    float* sinf = (float*)sin4;
    const int tid = threadIdx.x;
    const int token = tokens[0];
    {
        float e = emb[(size_t)token * H + tid];
        float h = h0[tid];
        sinf[tid]     = e;
        sinf[H + tid] = h;
        ws[WS_COMB_IN + tid] = e;          // embedded half of comb_in
    }
    __syncthreads();
    const int wave = tid >> 6, lane = tid & 63;
    #pragma unroll
    for (int s8 = 0; s8 < 8; ++s8) {
        const int l = wave * 8 + s8;
        const float4* wrow = (const float4*)(attn_W + (size_t)l * (2 * H));
        float acc = 0.f;
        #pragma unroll
        for (int it = 0; it < 8; ++it) {
            acc += dot4(wrow[lane + it * 64], sin4[lane + it * 64]);
        }
        acc = wave_sum(acc);
        if (lane == 0) sc[l] = acc + attn_b[l];
    }
    __syncthreads();
    if (wave == 0) {
        float s0 = sc[lane], s1 = sc[lane + 64];
        float m = fmaxf(s0, s1);
        #pragma unroll
        for (int off = 1; off < 64; off <<= 1) m = fmaxf(m, __shfl_xor(m, off));
        float e0 = expf(s0 - m), e1 = expf(s1 - m);
        float s = e0 + e1;
        #pragma unroll
        for (int off = 1; off < 64; off <<= 1) s += __shfl_xor(s, off);
        float inv = 1.f / s;
        float w0 = e0 * inv, w1 = e1 * inv;
        ws[WS_ATTN + lane]      = w0;
        ws[WS_ATTN + 64 + lane] = w1;
        dout[V + 2 * H + lane]      = w0;   // attn_weights output
        dout[V + 2 * H + 64 + lane] = w1;
    }
}

// K2a: attn_applied = attn_weights @ encoder_outputs. 4 blocks x 256.
__global__ __launch_bounds__(256) void k_attn_apply(const float* __restrict__ enc,
                                                    float* __restrict__ ws) {
    const int j = blockIdx.x * 256 + threadIdx.x;
    float a = 0.f;
    #pragma unroll 4
    for (int l = 0; l < L; ++l) a += ws[WS_ATTN + l] * enc[l * H + j];
    ws[WS_COMB_IN + H + j] = a;
}

// K2b: x = relu(comb_W @ comb_in + comb_b). 256 blocks x 256 (wave per row).
__global__ __launch_bounds__(256) void k_comb(const float* __restrict__ comb_W,
                                              const float* __restrict__ comb_b,
                                              float* __restrict__ ws) {
    const int wave = threadIdx.x >> 6, lane = threadIdx.x & 63;
    const int r = blockIdx.x * 4 + wave;
    const float4* wrow = (const float4*)(comb_W + (size_t)r * (2 * H));
    const float4* cin  = (const float4*)(ws + WS_COMB_IN);
    float acc = 0.f;
    #pragma unroll
    for (int it = 0; it < 8; ++it) acc += dot4(wrow[lane + it * 64], cin[lane + it * 64]);
    acc = wave_sum(acc);
    if (lane == 0) ws[WS_X + r] = fmaxf(acc + comb_b[r], 0.f);
}

// K3: LSTM cell. 1024 blocks x 256; block k computes gate rows {k, k+1024, k+2048, k+3072}.
__global__ __launch_bounds__(256) void k_lstm(const float* __restrict__ W_ih,
                                              const float* __restrict__ W_hh,
                                              const float* __restrict__ b_ih,
                                              const float* __restrict__ b_hh,
                                              const float* __restrict__ h0,
                                              const float* __restrict__ c0,
                                              float* __restrict__ ws,
                                              float* __restrict__ dout) {
    __shared__ float g[4];
    const int wave = threadIdx.x >> 6, lane = threadIdx.x & 63;
    const int k = blockIdx.x;
    const int row = wave * H + k;
    const float4* wi = (const float4*)(W_ih + (size_t)row * H);
    const float4* wh = (const float4*)(W_hh + (size_t)row * H);
    const float4* xv = (const float4*)(ws + WS_X);
    const float4* hv = (const float4*)h0;
    float acc = 0.f;
    #pragma unroll
    for (int it = 0; it < 4; ++it) {
        acc += dot4(wi[lane + it * 64], xv[lane + it * 64]);
        acc += dot4(wh[lane + it * 64], hv[lane + it * 64]);
    }
    acc = wave_sum(acc);
    if (lane == 0) g[wave] = acc + b_ih[row] + b_hh[row];
    __syncthreads();
    if (threadIdx.x == 0) {
        float gi = sigmoidf(g[0]);
        float gf = sigmoidf(g[1]);
        float gg = tanhf(g[2]);
        float go = sigmoidf(g[3]);
        float cn = gf * c0[k] + gi * gg;
        float hn = go * tanhf(cn);
        dout[V + k]     = hn;   // h_new output
        dout[V + H + k] = cn;   // c_new output
        ws[WS_H + k]    = hn;
    }
}

// K4a: logits = out_W @ h_new + out_b, plus per-block online-softmax partials.
// NB4 blocks x 256 (wave per row, 4 rows/block).
__global__ __launch_bounds__(256) void k_logits(const float* __restrict__ out_W,
                                                const float* __restrict__ out_b,
                                                float* __restrict__ ws) {
    __shared__ float z[4];
    const int wave = threadIdx.x >> 6, lane = threadIdx.x & 63;
    const int r = blockIdx.x * 4 + wave;
    float zz = -FLT_MAX;
    if (r < V) {
        const float4* wrow = (const float4*)(out_W + (size_t)r * H);
        const float4* hv   = (const float4*)(ws + WS_H);
        float acc = 0.f;
        #pragma unroll
        for (int it = 0; it < 4; ++it) acc += dot4(wrow[lane + it * 64], hv[lane + it * 64]);
        acc = wave_sum(acc);
        zz = acc + out_b[r];
        if (lane == 0) ws[WS_LOGITS + r] = zz;
    }
    if (lane == 0) z[wave] = zz;
    __syncthreads();
    if (threadIdx.x == 0) {
        float m = fmaxf(fmaxf(z[0], z[1]), fmaxf(z[2], z[3]));
        float s = expf(z[0] - m) + expf(z[1] - m) + expf(z[2] - m) + expf(z[3] - m);
        ws[WS_PM + blockIdx.x] = m;
        ws[WS_PS + blockIdx.x] = s;
    }
}

// K4b: merge per-block (m, s) partials -> global logsumexp. 1 block x 256.
__global__ __launch_bounds__(256) void k_lse(float* __restrict__ ws) {
    __shared__ float red[256];
    const int tid = threadIdx.x;
    float m = -FLT_MAX;
    for (int i = tid; i < NB4; i += 256) m = fmaxf(m, ws[WS_PM + i]);
    red[tid] = m;
    __syncthreads();
    #pragma unroll
    for (int s = 128; s > 0; s >>= 1) {
        if (tid < s) red[tid] = fmaxf(red[tid], red[tid + s]);
        __syncthreads();
    }
    const float M = red[0];
    __syncthreads();
    float s = 0.f;
    for (int i = tid; i < NB4; i += 256) s += ws[WS_PS + i] * expf(ws[WS_PM + i] - M);
    red[tid] = s;
    __syncthreads();
    #pragma unroll
    for (int st = 128; st > 0; st >>= 1) {
        if (tid < st) red[tid] += red[tid + st];
        __syncthreads();
    }
    if (tid == 0) ws[WS_LS] = M + logf(red[0]);
}

// K4c: out[v] = logits[v] - logsumexp.
__global__ __launch_bounds__(256) void k_lsm(const float* __restrict__ ws,
                                             float* __restrict__ dout) {
    const int v = blockIdx.x * 256 + threadIdx.x;
    if (v < V) dout[v] = ws[WS_LOGITS + v] - ws[WS_LS];
}

extern "C" void kernel_launch(void* const* d_in, const int* in_sizes, int n_in,
                              void* d_out, int out_size, void* d_ws, size_t ws_size,
                              hipStream_t stream) {
    const int*   tokens = (const int*)  d_in[0];
    const float* h0     = (const float*)d_in[1];
    const float* c0     = (const float*)d_in[2];
    const float* enc    = (const float*)d_in[3];
    const float* emb    = (const float*)d_in[4];
    const float* attn_W = (const float*)d_in[5];
    const float* attn_b = (const float*)d_in[6];
    const float* comb_W = (const float*)d_in[7];
    const float* comb_b = (const float*)d_in[8];
    const float* W_ih   = (const float*)d_in[9];
    const float* W_hh   = (const float*)d_in[10];
    const float* b_ih   = (const float*)d_in[11];
    const float* b_hh   = (const float*)d_in[12];
    const float* out_W  = (const float*)d_in[13];
    const float* out_b  = (const float*)d_in[14];
    float* dout = (float*)d_out;
    float* ws   = (float*)d_ws;

    k_attn<<<1, 1024, 0, stream>>>(tokens, h0, emb, attn_W, attn_b, ws, dout);
    k_attn_apply<<<4, 256, 0, stream>>>(enc, ws);
    k_comb<<<256, 256, 0, stream>>>(comb_W, comb_b, ws);
    k_lstm<<<H, 256, 0, stream>>>(W_ih, W_hh, b_ih, b_hh, h0, c0, ws, dout);
    k_logits<<<NB4, 256, 0, stream>>>(out_W, out_b, ws);
    k_lse<<<1, 256, 0, stream>>>(ws);
    k_lsm<<<(V + 255) / 256, 256, 0, stream>>>(ws, dout);
}